// Round 13
// baseline (1222.884 us; speedup 1.0000x reference)
//
#include <hip/hip_runtime.h>

// DeepRLSNet: batched RLS. B=64, N=T=2000, TAPS=64.
//
// R25 = RANK-4 ROUNDS: four Sherman-Morrison steps per barrier (500 rounds)
// vs R22's two (1000 rounds). Amortizes the measured ~1000cy/round fixed
// cost (barrier rendezvous + LDS exchange round-trip + scalar-gate latency)
// that R13..R24 proved irreducible per-round, over 2x the work.
//
// Construction (the 2-step kernel is the k=2 special case, verified term by
// term): at round start exchange 8 row-value vectors g_i=Q*x_i, h_i=QT*x_i
// (i=0..3, honest dots vs round-start Q). Post-barrier, 16 scalar dots
// m_ik = x_k.g_i (i<=k), n_ik = x_k.h_i (i<k) feed the correction recursion
//   A_k = g_k - sum_{i<k} sc_i*R_ik*A_i,  B_k = h_k - sum_{i<k} sc_i*P_ik*B_i
//   P_ik = A_i.x_k = m_ik - sum_{l<i} sc_l*R_li*P_lk
//   R_ik = B_i.x_k = n_ik - sum_{l<i} sc_l*P_li*R_lk
//   pd_k = m_kk - sum sc_i*R_ik*P_ik ; den_k = fma(sig,pd_k,lam_k);
//   sc_k = sig*rcp(den_k); sig *= 1/lam_k; y_k = wy_k + sum e_i*P_ik;
//   e_k = sc_k*(d_k - y_k)
// then 4 joint rank-1 updates Q -= sc_k A_k B_k^T (and transposed for QT,
// w += e_k A_k). QT==Q^T invariant preserved: row/slice recursions use the
// same fma forms with the same broadcast coefficients; update products are
// sign-symmetric ((-x)*y == x*(-y) bitwise) — same guarantee as the 2-step.
// Numerics: not bit-pinned vs R22 (deeper corrections for steps 2,3) but
// exact in real arithmetic; threshold headroom 8.5x (0.0156 vs 0.13375).
//
// Keeps: R22 fused-DPP quad_reduce, 1 barrier/round, parity LDS exchange,
// fused update+next-dots, deep x prefetch (ping-pong 4-row buffers, 1-round
// gap ~3000cy >> 900cy HBM latency), pd-first scalar overlap.

#define B_ 64
#define N_ 2000
#define TAPS_ 64
#define STEPS_ 2000
#define VST_ 72   // padded LDS vector stride; 2-way bank aliasing max (free)

typedef float f2 __attribute__((ext_vector_type(2)));

__device__ __forceinline__ f2 pk2(float v) { f2 r; r.x = v; r.y = v; return r; }

__device__ __forceinline__ void lds_barrier() {
    // LDS-only fence + barrier: global (vmcnt) prefetch stays in flight.
    asm volatile("s_waitcnt lgkmcnt(0)\n\ts_barrier" ::: "memory");
}

__device__ __forceinline__ float clipl(float v) {
    return fminf(fmaxf(v, 1e-4f), 0.9999f);
}

// sum over the 4 q-lanes of a quad, fused DPP adds with explicit
// 2-wait-state hazard guards (R22 pattern, HW-verified).
__device__ __forceinline__ float quad_reduce(float v) {
    float r;
    asm("s_nop 1\n\t"
        "v_add_f32_dpp %0, %1, %1 quad_perm:[1,0,3,2] row_mask:0xf bank_mask:0xf\n\t"
        "s_nop 1\n\t"
        "v_add_f32_dpp %0, %0, %0 quad_perm:[2,3,0,1] row_mask:0xf bank_mask:0xf"
        : "=&v"(r) : "v"(v));
    return r;   // bitwise-identical in all 4 lanes of the quad
}

// 1/v via v_rcp_f32 + one Newton step (~0.5 ulp).
__device__ __forceinline__ float rcp_nr(float v) {
    float r = __builtin_amdgcn_rcpf(v);
    float e = fmaf(-v, r, 1.0f);
    return fmaf(r, e, r);
}

__global__ __launch_bounds__(256, 1) void rls_kernel(
    const float* __restrict__ x_seq,   // [B, N, TAPS]
    const float* __restrict__ d_seq,   // [B, N]
    const float* __restrict__ lambdas, // [T]
    float* __restrict__ y_out,         // [B, N]
    float* __restrict__ w_out)         // [B, TAPS]
{
    const int b   = blockIdx.x;
    const int tid = threadIdx.x;
    const int r   = tid >> 2;    // row 0..63
    const int q   = tid & 3;     // quarter 0..3
    const int qb  = q << 4;

    // [parity][vec][VST_], vec 0..3 = g0..g3 (Q x_i), 4..7 = h0..h3 (QT x_i)
    __shared__ __align__(16) float  bufs[2][8][VST_];
    __shared__ __align__(16) float  d_lds[STEPS_];
    __shared__ __align__(16) float2 lam2[STEPS_];   // {clip(lam), rcp_nr(clip(lam))}

    const float* xb = x_seq + (size_t)b * N_ * TAPS_;
    const float* db = d_seq + (size_t)b * N_;

    for (int idx = tid; idx < STEPS_; idx += 256) {
        d_lds[idx] = db[idx];
        const float lc = clipl(lambdas[idx]);
        lam2[idx] = make_float2(lc, rcp_nr(lc));
    }

    f2 Q[8], QT[8], w[8];
    #pragma unroll
    for (int j = 0; j < 8; ++j) {
        Q[j].x = (qb + 2*j     == r) ? 1.0f : 0.0f;
        Q[j].y = (qb + 2*j + 1 == r) ? 1.0f : 0.0f;
        QT[j] = Q[j];
        w[j]  = pk2(0.0f);
    }
    float sig = 1.0f;   // P = sig * Q

    auto unpack4 = [](f2* dst, float4 v) {
        dst[0].x = v.x; dst[0].y = v.y; dst[1].x = v.z; dst[1].y = v.w;
    };

    // two ping-pong 4-row x buffers; round k uses one, prefetches the other.
    f2 XA[4][8], XB[4][8];
    auto loadquad = [&](f2 (&dst)[4][8], int row0) {
        #pragma unroll
        for (int i = 0; i < 4; ++i) {
            const float4* v = (const float4*)(xb + (size_t)(row0 + i) * TAPS_ + qb);
            #pragma unroll
            for (int j4 = 0; j4 < 4; ++j4)
                unpack4(&dst[i][2*j4], v[j4]);
        }
    };
    loadquad(XA, 0);

    // carried row values (this lane's row r) + w dots, produced by
    // prologue / previous round's fused next-dots.
    float g0rS, g1rS, g2rS, g3rS, h0rS, h1rS, h2rS, h3rS;
    float wy0S, wy1S, wy2S, wy3S;

    // ---- prologue: round 0's exchange data (honest dots vs Q=I, w=0) ----
    {
        f2 cg[4], ch[4], cw[4];
        #pragma unroll
        for (int i = 0; i < 4; ++i) { cg[i] = pk2(0.f); ch[i] = pk2(0.f); cw[i] = pk2(0.f); }
        #pragma unroll
        for (int j = 0; j < 8; ++j) {
            #pragma unroll
            for (int i = 0; i < 4; ++i) {
                cg[i] = __builtin_elementwise_fma(Q[j],  XA[i][j], cg[i]);
                ch[i] = __builtin_elementwise_fma(QT[j], XA[i][j], ch[i]);
                cw[i] = __builtin_elementwise_fma(w[j],  XA[i][j], cw[i]);
            }
        }
        g0rS = quad_reduce(cg[0].x + cg[0].y);
        g1rS = quad_reduce(cg[1].x + cg[1].y);
        g2rS = quad_reduce(cg[2].x + cg[2].y);
        g3rS = quad_reduce(cg[3].x + cg[3].y);
        h0rS = quad_reduce(ch[0].x + ch[0].y);
        h1rS = quad_reduce(ch[1].x + ch[1].y);
        h2rS = quad_reduce(ch[2].x + ch[2].y);
        h3rS = quad_reduce(ch[3].x + ch[3].y);
        wy0S = quad_reduce(cw[0].x + cw[0].y);
        wy1S = quad_reduce(cw[1].x + cw[1].y);
        wy2S = quad_reduce(cw[2].x + cw[2].y);
        wy3S = quad_reduce(cw[3].x + cw[3].y);
        const float gw = (q == 0) ? g0rS : (q == 1) ? g1rS : (q == 2) ? g2rS : g3rS;
        const float hw = (q == 0) ? h0rS : (q == 1) ? h1rS : (q == 2) ? h2rS : h3rS;
        bufs[0][q][r]     = gw;
        bufs[0][4 + q][r] = hw;
    }

    auto round = [&](int t, f2 (&xc)[4][8], f2 (&xn)[4][8],
                     int par, bool pf, bool fuse)
    {
        lds_barrier();   // exchange data (written last round) visible

        // ---- slice ds_reads: g0..g3 first (feed the early dots), then h ----
        f2 gs[4][8], hs[4][8];
        #pragma unroll
        for (int v = 0; v < 4; ++v) {
            const float4* p = (const float4*)(&bufs[par][v][qb]);
            #pragma unroll
            for (int j4 = 0; j4 < 4; ++j4)
                unpack4(&gs[v][2*j4], p[j4]);
        }
        #pragma unroll
        for (int v = 0; v < 4; ++v) {
            const float4* p = (const float4*)(&bufs[par][4 + v][qb]);
            #pragma unroll
            for (int j4 = 0; j4 < 4; ++j4)
                unpack4(&hs[v][2*j4], p[j4]);
        }
        const float4 lfA = *(const float4*)&lam2[t];      // {l0,1/l0,l1,1/l1}
        const float4 lfB = *(const float4*)&lam2[t + 2];  // {l2,1/l2,l3,1/l3}
        const float4 dd4 = *(const float4*)&d_lds[t];     // {d0,d1,d2,d3}

        // ---- deep prefetch: next round's 4 x-rows (global pipe) ----
        if (pf) loadquad(xn, t + 4);

        // ---- 16 scalar dots, ordered so den0->sc0 can start earliest ----
        auto dot = [&](const f2 (&a)[8], const f2 (&s)[8]) -> float {
            f2 acc = pk2(0.f);
            #pragma unroll
            for (int j = 0; j < 8; ++j)
                acc = __builtin_elementwise_fma(a[j], s[j], acc);
            return quad_reduce(acc.x + acc.y);
        };
        const float m00 = dot(xc[0], gs[0]);

        // k=0 scalars (overlap the remaining dot chains)
        const float den0 = fmaf(sig, m00, lfA.x);
        const float sc0  = sig * rcp_nr(den0);
        sig *= lfA.y;
        const float e0 = sc0 * (dd4.x - wy0S);

        const float m01 = dot(xc[1], gs[0]);
        const float n01 = dot(xc[1], hs[0]);
        const float m11 = dot(xc[1], gs[1]);

        const float P01 = m01, R01 = n01;
        const float nA01 = -(sc0 * R01), nB01 = -(sc0 * P01);

        // k=1
        const float pd1  = fmaf(nA01, P01, m11);
        const float den1 = fmaf(sig, pd1, lfA.z);
        const float sc1  = sig * rcp_nr(den1);
        sig *= lfA.w;
        const float y1v = fmaf(e0, P01, wy1S);
        const float e1  = sc1 * (dd4.y - y1v);

        const float m02 = dot(xc[2], gs[0]);
        const float n02 = dot(xc[2], hs[0]);
        const float m12 = dot(xc[2], gs[1]);
        const float n12 = dot(xc[2], hs[1]);
        const float m22 = dot(xc[2], gs[2]);

        const float P02 = m02, R02 = n02;
        const float nA02 = -(sc0 * R02), nB02 = -(sc0 * P02);
        const float P12 = fmaf(nA01, P02, m12);
        const float R12 = fmaf(nB01, R02, n12);
        const float nA12 = -(sc1 * R12), nB12 = -(sc1 * P12);

        // k=2
        const float pd2  = fmaf(nA12, P12, fmaf(nA02, P02, m22));
        const float den2 = fmaf(sig, pd2, lfB.x);
        const float sc2  = sig * rcp_nr(den2);
        sig *= lfB.y;
        const float y2v = fmaf(e1, P12, fmaf(e0, P02, wy2S));
        const float e2  = sc2 * (dd4.z - y2v);

        const float m03 = dot(xc[3], gs[0]);
        const float n03 = dot(xc[3], hs[0]);
        const float m13 = dot(xc[3], gs[1]);
        const float n13 = dot(xc[3], hs[1]);
        const float m23 = dot(xc[3], gs[2]);
        const float n23 = dot(xc[3], hs[2]);
        const float m33 = dot(xc[3], gs[3]);

        const float P03 = m03, R03 = n03;
        const float nA03 = -(sc0 * R03), nB03 = -(sc0 * P03);
        const float P13 = fmaf(nA01, P03, m13);
        const float R13 = fmaf(nB01, R03, n13);
        const float nA13 = -(sc1 * R13), nB13 = -(sc1 * P13);
        const float P23 = fmaf(nA12, P13, fmaf(nA02, P03, m23));
        const float R23 = fmaf(nB12, R13, fmaf(nB02, R03, n23));
        const float nA23 = -(sc2 * R23), nB23 = -(sc2 * P23);

        // k=3
        const float pd3  = fmaf(nA23, P23, fmaf(nA13, P13, fmaf(nA03, P03, m33)));
        const float den3 = fmaf(sig, pd3, lfB.z);
        const float sc3  = sig * rcp_nr(den3);
        sig *= lfB.w;
        const float y3v = fmaf(e2, P23, fmaf(e1, P13, fmaf(e0, P03, wy3S)));
        const float e3  = sc3 * (dd4.w - y3v);

        if (tid == 0)
            *(float4*)(y_out + (size_t)b * N_ + t) =
                make_float4(wy0S, y1v, y2v, y3v);

        // ---- row values A_kr, B_kr (same fma forms/coefs as slice build
        //      -> bitwise-consistent with slice elements, invariant holds) ----
        const float A0r = g0rS, B0r = h0rS;
        const float A1r = fmaf(nA01, A0r, g1rS);
        const float B1r = fmaf(nB01, B0r, h1rS);
        float A2r = fmaf(nA02, A0r, g2rS); A2r = fmaf(nA12, A1r, A2r);
        float B2r = fmaf(nB02, B0r, h2rS); B2r = fmaf(nB12, B1r, B2r);
        float A3r = fmaf(nA03, A0r, g3rS); A3r = fmaf(nA13, A1r, A3r); A3r = fmaf(nA23, A2r, A3r);
        float B3r = fmaf(nB03, B0r, h3rS); B3r = fmaf(nB13, B1r, B3r); B3r = fmaf(nB23, B2r, B3r);

        // broadcast coefficients
        const f2 nA01v = pk2(nA01), nA02v = pk2(nA02), nA03v = pk2(nA03);
        const f2 nA12v = pk2(nA12), nA13v = pk2(nA13), nA23v = pk2(nA23);
        const f2 nB01v = pk2(nB01), nB02v = pk2(nB02), nB03v = pk2(nB03);
        const f2 nB12v = pk2(nB12), nB13v = pk2(nB13), nB23v = pk2(nB23);
        const f2 e0v = pk2(e0), e1v = pk2(e1), e2v = pk2(e2), e3v = pk2(e3);
        const f2 sc0v = pk2(sc0), sc1v = pk2(sc1), sc2v = pk2(sc2), sc3v = pk2(sc3);
        const f2 nQ0v = pk2(-(sc0 * A0r)), nQ1v = pk2(-(sc1 * A1r));
        const f2 nQ2v = pk2(-(sc2 * A2r)), nQ3v = pk2(-(sc3 * A3r));
        const f2 nB0rv = pk2(-B0r), nB1rv = pk2(-B1r);
        const f2 nB2rv = pk2(-B2r), nB3rv = pk2(-B3r);

        f2 ng[4], nh[4], nw[4];
        #pragma unroll
        for (int i = 0; i < 4; ++i) { ng[i] = pk2(0.f); nh[i] = pk2(0.f); nw[i] = pk2(0.f); }

        // ---- fused: build A/B slices in place, apply 4 joint rank-1
        //      updates to w/Q/QT, accumulate next round's dots ----
        #pragma unroll
        for (int j = 0; j < 8; ++j) {
            // A slices (gs -> A_k), i ascending
            gs[1][j] = __builtin_elementwise_fma(nA01v, gs[0][j], gs[1][j]);
            gs[2][j] = __builtin_elementwise_fma(nA02v, gs[0][j], gs[2][j]);
            gs[2][j] = __builtin_elementwise_fma(nA12v, gs[1][j], gs[2][j]);
            gs[3][j] = __builtin_elementwise_fma(nA03v, gs[0][j], gs[3][j]);
            gs[3][j] = __builtin_elementwise_fma(nA13v, gs[1][j], gs[3][j]);
            gs[3][j] = __builtin_elementwise_fma(nA23v, gs[2][j], gs[3][j]);
            // B slices (hs -> B_k)
            hs[1][j] = __builtin_elementwise_fma(nB01v, hs[0][j], hs[1][j]);
            hs[2][j] = __builtin_elementwise_fma(nB02v, hs[0][j], hs[2][j]);
            hs[2][j] = __builtin_elementwise_fma(nB12v, hs[1][j], hs[2][j]);
            hs[3][j] = __builtin_elementwise_fma(nB03v, hs[0][j], hs[3][j]);
            hs[3][j] = __builtin_elementwise_fma(nB13v, hs[1][j], hs[3][j]);
            hs[3][j] = __builtin_elementwise_fma(nB23v, hs[2][j], hs[3][j]);
            // w += e_k A_k
            w[j] = __builtin_elementwise_fma(gs[0][j], e0v, w[j]);
            w[j] = __builtin_elementwise_fma(gs[1][j], e1v, w[j]);
            w[j] = __builtin_elementwise_fma(gs[2][j], e2v, w[j]);
            w[j] = __builtin_elementwise_fma(gs[3][j], e3v, w[j]);
            // Q[r][c] -= sc_k A_kr B_k[c]
            Q[j] = __builtin_elementwise_fma(nQ0v, hs[0][j], Q[j]);
            Q[j] = __builtin_elementwise_fma(nQ1v, hs[1][j], Q[j]);
            Q[j] = __builtin_elementwise_fma(nQ2v, hs[2][j], Q[j]);
            Q[j] = __builtin_elementwise_fma(nQ3v, hs[3][j], Q[j]);
            // QT[r][c] -= sc_k A_k[c] B_kr (sign-symmetric, same bits as Q^T)
            {
                f2 tq;
                tq = sc0v * gs[0][j]; QT[j] = __builtin_elementwise_fma(tq, nB0rv, QT[j]);
                tq = sc1v * gs[1][j]; QT[j] = __builtin_elementwise_fma(tq, nB1rv, QT[j]);
                tq = sc2v * gs[2][j]; QT[j] = __builtin_elementwise_fma(tq, nB2rv, QT[j]);
                tq = sc3v * gs[3][j]; QT[j] = __builtin_elementwise_fma(tq, nB3rv, QT[j]);
            }
            // next round's pre-dots on updated Q/QT/w
            if (fuse) {
                #pragma unroll
                for (int i = 0; i < 4; ++i) {
                    ng[i] = __builtin_elementwise_fma(Q[j],  xn[i][j], ng[i]);
                    nh[i] = __builtin_elementwise_fma(QT[j], xn[i][j], nh[i]);
                    nw[i] = __builtin_elementwise_fma(w[j],  xn[i][j], nw[i]);
                }
            }
        }

        if (fuse) {
            g0rS = quad_reduce(ng[0].x + ng[0].y);
            g1rS = quad_reduce(ng[1].x + ng[1].y);
            g2rS = quad_reduce(ng[2].x + ng[2].y);
            g3rS = quad_reduce(ng[3].x + ng[3].y);
            h0rS = quad_reduce(nh[0].x + nh[0].y);
            h1rS = quad_reduce(nh[1].x + nh[1].y);
            h2rS = quad_reduce(nh[2].x + nh[2].y);
            h3rS = quad_reduce(nh[3].x + nh[3].y);
            const float gw = (q == 0) ? g0rS : (q == 1) ? g1rS : (q == 2) ? g2rS : g3rS;
            const float hw = (q == 0) ? h0rS : (q == 1) ? h1rS : (q == 2) ? h2rS : h3rS;
            bufs[par ^ 1][q][r]     = gw;
            bufs[par ^ 1][4 + q][r] = hw;
            wy0S = quad_reduce(nw[0].x + nw[0].y);
            wy1S = quad_reduce(nw[1].x + nw[1].y);
            wy2S = quad_reduce(nw[2].x + nw[2].y);
            wy3S = quad_reduce(nw[3].x + nw[3].y);
        }
    };

    // 500 rounds of 4 steps; rounds 0..497 in the 2-unrolled loop.
    for (int t = 0; t < 1992; t += 8) {
        round(t,     XA, XB, 0, true, true);
        round(t + 4, XB, XA, 1, true, true);
    }
    // round 498 (t=1992): prefetches rows 1996..1999, fused dots for 499.
    round(1992, XA, XB, 0, true,  true);
    // round 499 (t=1996): final; no prefetch, no fusion.
    round(1996, XB, XA, 1, false, false);

    // ---- final weights: row-group 0 holds a full replica across q ----
    if (r == 0) {
        float4* wo = (float4*)(w_out + (size_t)b * TAPS_ + qb);
        #pragma unroll
        for (int j4 = 0; j4 < 4; ++j4)
            wo[j4] = make_float4(w[2*j4].x, w[2*j4].y, w[2*j4+1].x, w[2*j4+1].y);
    }
}

extern "C" void kernel_launch(void* const* d_in, const int* in_sizes, int n_in,
                              void* d_out, int out_size, void* d_ws, size_t ws_size,
                              hipStream_t stream) {
    const float* x_seq   = (const float*)d_in[0];
    const float* d_seq   = (const float*)d_in[1];
    const float* lambdas = (const float*)d_in[2];

    float* y_out = (float*)d_out;                      // B*N floats
    float* w_out = (float*)d_out + (size_t)B_ * N_;    // B*TAPS floats

    rls_kernel<<<B_, 256, 0, stream>>>(x_seq, d_seq, lambdas, y_out, w_out);
}